// Round 16
// baseline (51.766 us; speedup 1.0000x reference)
//
#include <hip/hip_runtime.h>

#define DIM   256
#define CLS   512
#define NGF   32640          // packed strict-upper-triangle floats per class
#define NQ    8160           // NGF/4 float4 quads
#define NITER 5
#define PSH   72             // y part-slice stride in h16

typedef _Float16 h16;
typedef __attribute__((ext_vector_type(2))) _Float16 h16x2;

__device__ __forceinline__ float dot2f(unsigned a, unsigned b, float c) {
    return __builtin_amdgcn_fdot2(__builtin_bit_cast(h16x2, a),
                                  __builtin_bit_cast(h16x2, b), c, false);
}

__device__ __forceinline__ unsigned pkrtz(float lo, float hi) {
    return __builtin_bit_cast(unsigned, __builtin_amdgcn_cvt_pkrtz(lo, hi));
}

__device__ __forceinline__ uint2 cvt2(float4 v) {
    uint2 d;
    d.x = pkrtz(0.5f * v.x, 0.5f * v.y);
    d.y = pkrtz(0.5f * v.z, 0.5f * v.w);
    return d;
}

// barrier draining LDS only
__device__ __forceinline__ void bar_lds() {
    asm volatile("s_waitcnt lgkmcnt(0)\n\ts_barrier" ::: "memory");
}

// y[g] at part(g)*PSH + slot(g): part=(g>>4)&3, slot=((g>>6)<<4)|(g&15)
__device__ __forceinline__ int yaddr(int g) {
    return ((g >> 4) & 3) * PSH + (((g >> 6) << 4) | (g & 15));
}

// one 16-col gather chunk A -> sreg[8A..8A+7] (conflict-free chunked parts)
#define GCHUNK(BASE, A)                                                   \
    do {                                                                  \
        int g_  = 64 * (A) + 16 * p;                                      \
        int au_ = offr + g_;                                              \
        int al_ = ((g_ * (511 - g_)) >> 1) + r - g_ - 1;                  \
        unsigned wacc_ = 0;                                               \
        _Pragma("unroll")                                                 \
        for (int t_ = 0; t_ < 16; ++t_) {                                 \
            int idx_ = (g_ < r) ? al_ : au_;                              \
            idx_ = idx_ < 0 ? 0 : idx_;                                   \
            unsigned h_ = (BASE)[idx_];                                   \
            h_ = (g_ < r) ? (h_ ^ 0x8000u) : h_;                          \
            h_ = (g_ == r) ? 0u : h_;                                     \
            if (t_ & 1) { wacc_ |= h_ << 16; sreg[(16*(A)+t_) >> 1] = wacc_; } \
            else       { wacc_  = h_; }                                   \
            ++au_;                                                        \
            al_ += 254 - g_;                                              \
            ++g_;                                                         \
        }                                                                 \
    } while (0)

#define DOTS(V)                                                           \
    float V;                                                              \
    do {                                                                  \
        float a0_ = 0.f, a1_ = 0.f, a2_ = 0.f, a3_ = 0.f;                 \
        _Pragma("unroll")                                                 \
        for (int k_ = 0; k_ < 8; ++k_) {                                  \
            uint4 yv_ = yp[k_];                                           \
            a0_ = dot2f(sreg[4*k_+0], yv_.x, a0_);                        \
            a1_ = dot2f(sreg[4*k_+1], yv_.y, a1_);                        \
            a2_ = dot2f(sreg[4*k_+2], yv_.z, a2_);                        \
            a3_ = dot2f(sreg[4*k_+3], yv_.w, a3_);                        \
        }                                                                 \
        V = (a0_ + a1_) + (a2_ + a3_);                                    \
        V += __shfl_xor(V, 1);                                            \
        V += __shfl_xor(V, 2);                                            \
    } while (0)

__global__ void __launch_bounds__(1024)
cayley_kernel(const float* __restrict__ x, const float* __restrict__ W,
              float* __restrict__ out) {
    extern __shared__ char smem[];
    unsigned short* U  = (unsigned short*)smem;        // 65536 B f16(0.5*W), reused A->B
    uint2*          U2 = (uint2*)smem;
    h16* sy0 = (h16*)(smem + 65536);                   // 576 B
    h16* sy1 = sy0 + 4 * PSH;                          // 576 B

    const int tid  = threadIdx.x;
    const int r    = tid >> 2;       // row 0..255
    const int p    = tid & 3;        // part: owns columns {64a + 16p + t}
    const int cA   = blockIdx.x;
    const int cB   = blockIdx.x + 256;
    const int offr = (r * (511 - r)) / 2 - r - 1;
    const int wr   = yaddr(r);

    const float xrA = x[(size_t)r * CLS + cA];
    unsigned sreg[32];

    // ===== stage A: global f32 -> f16(0.5w) -> U, coalesced =====
    {
        const float4* WA4 = (const float4*)(W + (size_t)cA * NGF);
        #pragma unroll
        for (int k = 0; k < 8; ++k) {
            int q = tid + 1024 * k;
            U2[q] = cvt2(WA4[q < NQ ? q : 0]);
        }
    }
    if (p == 0) sy0[wr] = (h16)xrA;
    __syncthreads();                        // U(A) + y0(A) visible

    GCHUNK(U, 0); GCHUNK(U, 1); GCHUNK(U, 2); GCHUNK(U, 3);
    __syncthreads();                        // gathers done -> U region dead

    // ===== iterate A; B staged transiently 2 chunks/iter (it=0..3) =====
    const float4* WB4 = (const float4*)(W + (size_t)cB * NGF);
    {
        #pragma unroll
        for (int it = 0; it < NITER; ++it) {
            const h16* ycur = (it & 1) ? sy1 : sy0;
            h16*       ynxt = (it & 1) ? sy0 : sy1;
            const uint4* yp = (const uint4*)(ycur + p * PSH);
            float4 b0, b1;
            int q0 = 0, q1 = 0;
            if (it < 4) {                   // issue loads BEFORE dots (latency hides)
                q0 = tid + 1024 * (2 * it);
                q1 = tid + 1024 * (2 * it + 1);
                b0 = WB4[q0 < NQ ? q0 : 0];
                b1 = WB4[q1 < NQ ? q1 : 0];
            }
            DOTS(v);
            if (it < 4) {                   // consume: cvt + ds_write (transient)
                U2[q0] = cvt2(b0);
                U2[q1] = cvt2(b1);
            }
            if (it < NITER - 1) {
                if (p == 0) ynxt[wr] = (h16)(xrA - v);
                bar_lds();
            } else {
                if (p == 0) out[(size_t)r * CLS + cA] = xrA - 2.f * v;
            }
        }
    }
    __syncthreads();                        // U(B) complete; A y-reads done

    // ===== class B =====
    const float xrB = x[(size_t)r * CLS + cB];
    GCHUNK(U, 0); GCHUNK(U, 1); GCHUNK(U, 2); GCHUNK(U, 3);
    if (p == 0) sy0[wr] = (h16)xrB;
    bar_lds();                              // y0(B) visible

    {
        #pragma unroll
        for (int it = 0; it < NITER; ++it) {
            const h16* ycur = (it & 1) ? sy1 : sy0;
            h16*       ynxt = (it & 1) ? sy0 : sy1;
            const uint4* yp = (const uint4*)(ycur + p * PSH);
            DOTS(v);
            if (it < NITER - 1) {
                if (p == 0) ynxt[wr] = (h16)(xrB - v);
                bar_lds();
            } else {
                if (p == 0) out[(size_t)r * CLS + cB] = xrB - 2.f * v;
            }
        }
    }
}

extern "C" void kernel_launch(void* const* d_in, const int* in_sizes, int n_in,
                              void* d_out, int out_size, void* d_ws, size_t ws_size,
                              hipStream_t stream) {
    const float* x = (const float*)d_in[0];
    const float* W = (const float*)d_in[1];
    float* out = (float*)d_out;

    const size_t smem = 65536 + 2 * 4 * PSH * 2;   // 66688 B
    hipFuncSetAttribute((const void*)cayley_kernel,
                        hipFuncAttributeMaxDynamicSharedMemorySize, (int)smem);
    hipLaunchKernelGGL(cayley_kernel, dim3(CLS / 2), dim3(1024), smem, stream, x, W, out);
}

// Round 17
// 49.632 us; speedup vs baseline: 1.0430x; 1.0430x over previous
//
#include <hip/hip_runtime.h>

#define DIM   256
#define CLS   512
#define NGF   32640          // packed strict-upper-triangle floats per class
#define NQ    8160           // NGF/4 float4 quads
#define NITER 5
#define PSH   72             // y part-slice stride in h16

typedef _Float16 h16;
typedef __attribute__((ext_vector_type(2))) _Float16 h16x2;

__device__ __forceinline__ float dot2f(unsigned a, unsigned b, float c) {
    return __builtin_amdgcn_fdot2(__builtin_bit_cast(h16x2, a),
                                  __builtin_bit_cast(h16x2, b), c, false);
}

__device__ __forceinline__ unsigned pkrtz(float lo, float hi) {
    return __builtin_bit_cast(unsigned, __builtin_amdgcn_cvt_pkrtz(lo, hi));
}

__device__ __forceinline__ uint2 cvt2(float4 v) {
    uint2 d;
    d.x = pkrtz(0.5f * v.x, 0.5f * v.y);
    d.y = pkrtz(0.5f * v.z, 0.5f * v.w);
    return d;
}

// barrier draining LDS only
__device__ __forceinline__ void bar_lds() {
    asm volatile("s_waitcnt lgkmcnt(0)\n\ts_barrier" ::: "memory");
}

// y[g] at part(g)*PSH + slot(g): part=(g>>4)&3, slot=((g>>6)<<4)|(g&15)
__device__ __forceinline__ int yaddr(int g) {
    return ((g >> 4) & 3) * PSH + (((g >> 6) << 4) | (g & 15));
}

// one 16-col gather chunk A -> sreg[8A..8A+7] (conflict-free chunked parts)
#define GCHUNK(BASE, A)                                                   \
    do {                                                                  \
        int g_  = 64 * (A) + 16 * p;                                      \
        int au_ = offr + g_;                                              \
        int al_ = ((g_ * (511 - g_)) >> 1) + r - g_ - 1;                  \
        unsigned wacc_ = 0;                                               \
        _Pragma("unroll")                                                 \
        for (int t_ = 0; t_ < 16; ++t_) {                                 \
            int idx_ = (g_ < r) ? al_ : au_;                              \
            idx_ = idx_ < 0 ? 0 : idx_;                                   \
            unsigned h_ = (BASE)[idx_];                                   \
            h_ = (g_ < r) ? (h_ ^ 0x8000u) : h_;                          \
            h_ = (g_ == r) ? 0u : h_;                                     \
            if (t_ & 1) { wacc_ |= h_ << 16; sreg[(16*(A)+t_) >> 1] = wacc_; } \
            else       { wacc_  = h_; }                                   \
            ++au_;                                                        \
            al_ += 254 - g_;                                              \
            ++g_;                                                         \
        }                                                                 \
    } while (0)

// batched dot: 4 batches of 2 ds_read_b128 (8 y-regs live, not 32);
// sched_barrier(0) pins each batch so the scheduler can't re-hoist all loads
#define DOTSB(V)                                                          \
    float V;                                                              \
    do {                                                                  \
        float a0_ = 0.f, a1_ = 0.f, a2_ = 0.f, a3_ = 0.f;                 \
        _Pragma("unroll")                                                 \
        for (int b_ = 0; b_ < 4; ++b_) {                                  \
            uint4 y0_ = yp[2*b_], y1_ = yp[2*b_+1];                       \
            a0_ = dot2f(sreg[8*b_+0], y0_.x, a0_);                        \
            a1_ = dot2f(sreg[8*b_+1], y0_.y, a1_);                        \
            a2_ = dot2f(sreg[8*b_+2], y0_.z, a2_);                        \
            a3_ = dot2f(sreg[8*b_+3], y0_.w, a3_);                        \
            a0_ = dot2f(sreg[8*b_+4], y1_.x, a0_);                        \
            a1_ = dot2f(sreg[8*b_+5], y1_.y, a1_);                        \
            a2_ = dot2f(sreg[8*b_+6], y1_.z, a2_);                        \
            a3_ = dot2f(sreg[8*b_+7], y1_.w, a3_);                        \
            __builtin_amdgcn_sched_barrier(0);                            \
        }                                                                 \
        V = (a0_ + a1_) + (a2_ + a3_);                                    \
        V += __shfl_xor(V, 1);                                            \
        V += __shfl_xor(V, 2);                                            \
    } while (0)

__global__ void __launch_bounds__(1024)
cayley_kernel(const float* __restrict__ x, const float* __restrict__ W,
              float* __restrict__ out) {
    extern __shared__ char smem[];
    unsigned short* U  = (unsigned short*)smem;        // 65536 B f16(0.5*W), reused A->B
    uint2*          U2 = (uint2*)smem;
    h16* sy0 = (h16*)(smem + 65536);                   // 576 B
    h16* sy1 = sy0 + 4 * PSH;                          // 576 B

    const int tid  = threadIdx.x;
    const int r    = tid >> 2;       // row 0..255
    const int p    = tid & 3;        // part: owns columns {64a + 16p + t}
    const int cA   = blockIdx.x;
    const int cB   = blockIdx.x + 256;
    const int offr = (r * (511 - r)) / 2 - r - 1;
    const int wr   = yaddr(r);

    const float xrA = x[(size_t)r * CLS + cA];
    unsigned sreg[32];

    // ===== stage A: global f32 -> f16(0.5w) -> U, coalesced =====
    {
        const float4* WA4 = (const float4*)(W + (size_t)cA * NGF);
        #pragma unroll
        for (int k = 0; k < 8; ++k) {
            int q = tid + 1024 * k;
            U2[q] = cvt2(WA4[q < NQ ? q : 0]);
        }
    }
    if (p == 0) sy0[wr] = (h16)xrA;
    __syncthreads();                        // U(A) + y0(A) visible

    GCHUNK(U, 0); GCHUNK(U, 1); GCHUNK(U, 2); GCHUNK(U, 3);
    __syncthreads();                        // gathers done -> U region dead

    // ===== iterate A; B staged transiently 2 chunks/iter (it=0..3) =====
    const float4* WB4 = (const float4*)(W + (size_t)cB * NGF);
    {
        #pragma unroll
        for (int it = 0; it < NITER; ++it) {
            const h16* ycur = (it & 1) ? sy1 : sy0;
            h16*       ynxt = (it & 1) ? sy0 : sy1;
            const uint4* yp = (const uint4*)(ycur + p * PSH);
            float4 b0, b1;
            int q0 = 0, q1 = 0;
            if (it < 4) {                   // issue loads BEFORE dots (latency hides)
                q0 = tid + 1024 * (2 * it);
                q1 = q0 + 1024;
                b0 = WB4[q0 < NQ ? q0 : 0];
                b1 = WB4[q1 < NQ ? q1 : 0];
            }
            DOTSB(v);
            if (it < 4) {                   // consume AFTER last sched_barrier
                U2[q0] = cvt2(b0);
                U2[q1] = cvt2(b1);
            }
            if (it < NITER - 1) {
                if (p == 0) ynxt[wr] = (h16)(xrA - v);
                bar_lds();
            } else {
                if (p == 0) out[(size_t)r * CLS + cA] = xrA - 2.f * v;
            }
        }
    }
    __syncthreads();                        // U(B) complete; A y-reads done

    // ===== class B =====
    const float xrB = x[(size_t)r * CLS + cB];
    GCHUNK(U, 0); GCHUNK(U, 1); GCHUNK(U, 2); GCHUNK(U, 3);
    if (p == 0) sy0[wr] = (h16)xrB;
    bar_lds();                              // y0(B) visible

    {
        #pragma unroll
        for (int it = 0; it < NITER; ++it) {
            const h16* ycur = (it & 1) ? sy1 : sy0;
            h16*       ynxt = (it & 1) ? sy0 : sy1;
            const uint4* yp = (const uint4*)(ycur + p * PSH);
            DOTSB(v);
            if (it < NITER - 1) {
                if (p == 0) ynxt[wr] = (h16)(xrB - v);
                bar_lds();
            } else {
                if (p == 0) out[(size_t)r * CLS + cB] = xrB - 2.f * v;
            }
        }
    }
}

extern "C" void kernel_launch(void* const* d_in, const int* in_sizes, int n_in,
                              void* d_out, int out_size, void* d_ws, size_t ws_size,
                              hipStream_t stream) {
    const float* x = (const float*)d_in[0];
    const float* W = (const float*)d_in[1];
    float* out = (float*)d_out;

    const size_t smem = 65536 + 2 * 4 * PSH * 2;   // 66688 B
    hipFuncSetAttribute((const void*)cayley_kernel,
                        hipFuncAttributeMaxDynamicSharedMemorySize, (int)smem);
    hipLaunchKernelGGL(cayley_kernel, dim3(CLS / 2), dim3(1024), smem, stream, x, W, out);
}

// Round 18
// 48.232 us; speedup vs baseline: 1.0733x; 1.0290x over previous
//
#include <hip/hip_runtime.h>

#define DIM   256
#define CLS   512
#define NGF   32640          // packed strict-upper-triangle floats per class
#define NQ    8160           // NGF/4 float4 quads
#define NITER 5
#define PSH   72             // y part-slice stride in h16

typedef _Float16 h16;
typedef __attribute__((ext_vector_type(2))) _Float16 h16x2;

__device__ __forceinline__ float dot2f(unsigned a, unsigned b, float c) {
    return __builtin_amdgcn_fdot2(__builtin_bit_cast(h16x2, a),
                                  __builtin_bit_cast(h16x2, b), c, false);
}

__device__ __forceinline__ unsigned pkrtz(float lo, float hi) {
    return __builtin_bit_cast(unsigned, __builtin_amdgcn_cvt_pkrtz(lo, hi));
}

__device__ __forceinline__ uint2 cvt2(float4 v) {
    uint2 d;
    d.x = pkrtz(0.5f * v.x, 0.5f * v.y);
    d.y = pkrtz(0.5f * v.z, 0.5f * v.w);
    return d;
}

// barrier draining LDS only
__device__ __forceinline__ void bar_lds() {
    asm volatile("s_waitcnt lgkmcnt(0)\n\ts_barrier" ::: "memory");
}

// y[g] at part(g)*PSH + slot(g): part=(g>>4)&3, slot=((g>>6)<<4)|(g&15)
__device__ __forceinline__ int yaddr(int g) {
    return ((g >> 4) & 3) * PSH + (((g >> 6) << 4) | (g & 15));
}

// transient B-staging slot: load 1 chunk, cvt, write; fenced both sides so it
// cannot be hoisted across (or live through) neighboring compute blocks
#define BSLOT(CH)                                                         \
    do {                                                                  \
        __builtin_amdgcn_sched_barrier(0);                                \
        int q_ = tid + 1024 * (CH);                                       \
        float4 b_ = WB4[q_ < NQ ? q_ : 0];                                \
        if (q_ < NQ) U2[q_] = cvt2(b_);                                   \
        __builtin_amdgcn_sched_barrier(0);                                \
    } while (0)

// one 16-col gather chunk A -> sreg[8A..8A+7] (conflict-free chunked parts)
#define GCHUNK(BASE, A)                                                   \
    do {                                                                  \
        int g_  = 64 * (A) + 16 * p;                                      \
        int au_ = offr + g_;                                              \
        int al_ = ((g_ * (511 - g_)) >> 1) + r - g_ - 1;                  \
        unsigned wacc_ = 0;                                               \
        _Pragma("unroll")                                                 \
        for (int t_ = 0; t_ < 16; ++t_) {                                 \
            int idx_ = (g_ < r) ? al_ : au_;                              \
            idx_ = idx_ < 0 ? 0 : idx_;                                   \
            unsigned h_ = (BASE)[idx_];                                   \
            h_ = (g_ < r) ? (h_ ^ 0x8000u) : h_;                          \
            h_ = (g_ == r) ? 0u : h_;                                     \
            if (t_ & 1) { wacc_ |= h_ << 16; sreg[(16*(A)+t_) >> 1] = wacc_; } \
            else       { wacc_  = h_; }                                   \
            ++au_;                                                        \
            al_ += 254 - g_;                                              \
            ++g_;                                                         \
        }                                                                 \
    } while (0)

#define DOTS(V)                                                           \
    float V;                                                              \
    do {                                                                  \
        float a0_ = 0.f, a1_ = 0.f, a2_ = 0.f, a3_ = 0.f;                 \
        _Pragma("unroll")                                                 \
        for (int k_ = 0; k_ < 8; ++k_) {                                  \
            uint4 yv_ = yp[k_];                                           \
            a0_ = dot2f(sreg[4*k_+0], yv_.x, a0_);                        \
            a1_ = dot2f(sreg[4*k_+1], yv_.y, a1_);                        \
            a2_ = dot2f(sreg[4*k_+2], yv_.z, a2_);                        \
            a3_ = dot2f(sreg[4*k_+3], yv_.w, a3_);                        \
        }                                                                 \
        V = (a0_ + a1_) + (a2_ + a3_);                                    \
        V += __shfl_xor(V, 1);                                            \
        V += __shfl_xor(V, 2);                                            \
    } while (0)

__global__ void __launch_bounds__(1024)
cayley_kernel(const float* __restrict__ x, const float* __restrict__ W,
              float* __restrict__ out) {
    extern __shared__ char smem[];
    unsigned short* U  = (unsigned short*)smem;        // 65536 B f16(0.5*W), reused A->B
    uint2*          U2 = (uint2*)smem;
    h16* sy0 = (h16*)(smem + 65536);                   // 576 B
    h16* sy1 = sy0 + 4 * PSH;                          // 576 B

    const int tid  = threadIdx.x;
    const int r    = tid >> 2;       // row 0..255
    const int p    = tid & 3;        // part: owns columns {64a + 16p + t}
    const int cA   = blockIdx.x;
    const int cB   = blockIdx.x + 256;
    const int offr = (r * (511 - r)) / 2 - r - 1;
    const int wr   = yaddr(r);

    const float xrA = x[(size_t)r * CLS + cA];
    unsigned sreg[32];

    // ===== stage A: global f32 -> f16(0.5w) -> U, coalesced =====
    {
        const float4* WA4 = (const float4*)(W + (size_t)cA * NGF);
        #pragma unroll
        for (int k = 0; k < 8; ++k) {
            int q = tid + 1024 * k;
            U2[q] = cvt2(WA4[q < NQ ? q : 0]);
        }
    }
    if (p == 0) sy0[wr] = (h16)xrA;
    __syncthreads();                        // U(A) + y0(A) visible

    // NOTE: B-chunks 0-3 overwrite U[0..4096) which GCHUNKs still read!
    // Safe ordering: GCHUNK(A) reads columns everywhere in U; so B-slots must
    // come only AFTER all 4 gathers. Instead weave B 0-3 between gathers of
    // DIFFERENT regions is unsafe -> put all 4 after the gather barrier,
    // before iterate (still overlaps: loads issue back-to-back, writes are
    // cheap; HBM streams while iterate runs via wave interleaving).
    GCHUNK(U, 0); GCHUNK(U, 1); GCHUNK(U, 2); GCHUNK(U, 3);
    __syncthreads();                        // gathers done -> U region dead

    const float4* WB4 = (const float4*)(W + (size_t)cB * NGF);
    BSLOT(0); BSLOT(1); BSLOT(2); BSLOT(3);

    // ===== iterate A; remaining B chunks in post-DOTS gaps =====
    {
        #pragma unroll
        for (int it = 0; it < NITER; ++it) {
            const h16* ycur = (it & 1) ? sy1 : sy0;
            h16*       ynxt = (it & 1) ? sy0 : sy1;
            const uint4* yp = (const uint4*)(ycur + p * PSH);
            DOTS(v);
            if (it < 4) BSLOT(4 + it);      // transient: nothing lives across DOTS
            if (it < NITER - 1) {
                if (p == 0) ynxt[wr] = (h16)(xrA - v);
                bar_lds();
            } else {
                if (p == 0) out[(size_t)r * CLS + cA] = xrA - 2.f * v;
            }
        }
    }
    __syncthreads();                        // U(B) complete; A y-reads done

    // ===== class B =====
    const float xrB = x[(size_t)r * CLS + cB];
    GCHUNK(U, 0); GCHUNK(U, 1); GCHUNK(U, 2); GCHUNK(U, 3);
    if (p == 0) sy0[wr] = (h16)xrB;
    bar_lds();                              // y0(B) visible

    {
        #pragma unroll
        for (int it = 0; it < NITER; ++it) {
            const h16* ycur = (it & 1) ? sy1 : sy0;
            h16*       ynxt = (it & 1) ? sy0 : sy1;
            const uint4* yp = (const uint4*)(ycur + p * PSH);
            DOTS(v);
            if (it < NITER - 1) {
                if (p == 0) ynxt[wr] = (h16)(xrB - v);
                bar_lds();
            } else {
                if (p == 0) out[(size_t)r * CLS + cB] = xrB - 2.f * v;
            }
        }
    }
}

extern "C" void kernel_launch(void* const* d_in, const int* in_sizes, int n_in,
                              void* d_out, int out_size, void* d_ws, size_t ws_size,
                              hipStream_t stream) {
    const float* x = (const float*)d_in[0];
    const float* W = (const float*)d_in[1];
    float* out = (float*)d_out;

    const size_t smem = 65536 + 2 * 4 * PSH * 2;   // 66688 B
    hipFuncSetAttribute((const void*)cayley_kernel,
                        hipFuncAttributeMaxDynamicSharedMemorySize, (int)smem);
    hipLaunchKernelGGL(cayley_kernel, dim3(CLS / 2), dim3(1024), smem, stream, x, W, out);
}

// Round 19
// 26.486 us; speedup vs baseline: 1.9545x; 1.8211x over previous
//
#include <hip/hip_runtime.h>

#define DIM   256
#define CLS   512
#define NGF   32640          // packed strict-upper-triangle floats per class
#define NQ    8160           // NGF/4 float4 quads
#define NITER 4
#define PSH   72             // y part-slice stride in h16

typedef _Float16 h16;
typedef __attribute__((ext_vector_type(2))) _Float16 h16x2;

__device__ __forceinline__ float dot2f(unsigned a, unsigned b, float c) {
    return __builtin_amdgcn_fdot2(__builtin_bit_cast(h16x2, a),
                                  __builtin_bit_cast(h16x2, b), c, false);
}

__device__ __forceinline__ unsigned pkrtz(float lo, float hi) {
    return __builtin_bit_cast(unsigned, __builtin_amdgcn_cvt_pkrtz(lo, hi));
}

// barrier draining LDS only
__device__ __forceinline__ void bar_lds() {
    asm volatile("s_waitcnt lgkmcnt(0)\n\ts_barrier" ::: "memory");
}

// y[g] at part(g)*PSH + slot(g): part=(g>>4)&3, slot=((g>>6)<<4)|(g&15)
__device__ __forceinline__ int yaddr(int g) {
    return ((g >> 4) & 3) * PSH + (((g >> 6) << 4) | (g & 15));
}

__global__ void __launch_bounds__(1024)
cayley_kernel(const float* __restrict__ x, const float* __restrict__ W,
              float* __restrict__ out) {
    extern __shared__ char smem[];
    unsigned short* U  = (unsigned short*)smem;        // 65536 B: f16(0.5*W) packed triu
    unsigned*       Ud = (unsigned*)smem;              // dword view of U
    uint2*          U2 = (uint2*)smem;
    h16* sy0 = (h16*)(smem + 65536);                   // 576 B
    h16* sy1 = sy0 + 4 * PSH;                          // 576 B

    const int tid  = threadIdx.x;
    const int r    = tid >> 2;       // row 0..255
    const int p    = tid & 3;        // part: owns columns {64a + 16p + t}
    const int c    = blockIdx.x;
    const int offr = (r * (511 - r)) / 2 - r - 1;      // off(r) - r - 1

    // ===== stage packed W -> LDS as f16 (0.5*w), coalesced =====
    {
        const float4* Wc4 = (const float4*)(W + (size_t)c * NGF);
        #pragma unroll
        for (int k = 0; k < 8; ++k) {
            int q = tid + 1024 * k;
            float4 v = Wc4[q < NQ ? q : 0];
            uint2 d;
            d.x = pkrtz(0.5f * v.x, 0.5f * v.y);
            d.y = pkrtz(0.5f * v.z, 0.5f * v.w);
            U2[q] = d;
        }
    }
    const float xr = x[(size_t)r * CLS + c];
    if (p == 0) sy0[yaddr(r)] = (h16)xr;
    __syncthreads();                                   // U + y0 visible

    // ===== gather S[r][g] for owned columns -> sreg (f16x2), 3-path =====
    unsigned sreg[32];
    {
        #pragma unroll
        for (int a = 0; a < 4; ++a) {
            const int g0 = 64 * a + 16 * p;
            if (g0 > r) {
                // ---- pure upper: contiguous U[au0..au0+15], vectorized ----
                int au0 = offr + g0;
                unsigned d[9];
                #pragma unroll
                for (int i = 0; i < 9; ++i) d[i] = Ud[(au0 >> 1) + i];
                const bool odd = (au0 & 1);
                #pragma unroll
                for (int i = 0; i < 8; ++i) {
                    unsigned ev = d[i];
                    unsigned od = __builtin_amdgcn_alignbit(d[i + 1], d[i], 16);
                    sreg[8 * a + i] = odd ? od : ev;
                }
            } else if (g0 + 15 < r) {
                // ---- pure lower: strided scalar, negate, no clamps ----
                int g  = g0;
                int al = ((g0 * (511 - g0)) >> 1) + r - g0 - 1;
                unsigned wacc = 0;
                #pragma unroll
                for (int t = 0; t < 16; ++t) {
                    unsigned h = U[al] ^ 0x8000u;
                    if (t & 1) { wacc |= h << 16; sreg[8 * a + (t >> 1)] = wacc; }
                    else       { wacc  = h; }
                    al += 254 - g;
                    ++g;
                }
            } else {
                // ---- mixed (contains diagonal): general scalar path ----
                int g  = g0;
                int au = offr + g0;
                int al = ((g0 * (511 - g0)) >> 1) + r - g0 - 1;
                unsigned wacc = 0;
                #pragma unroll
                for (int t = 0; t < 16; ++t) {
                    int idx = (g < r) ? al : au;
                    idx = idx < 0 ? 0 : idx;           // only r==g==0 hits -1
                    unsigned h = U[idx];
                    h = (g < r) ? (h ^ 0x8000u) : h;
                    h = (g == r) ? 0u : h;
                    if (t & 1) { wacc |= h << 16; sreg[8 * a + (t >> 1)] = wacc; }
                    else       { wacc  = h; }
                    ++au;
                    al += 254 - g;
                    ++g;
                }
            }
        }
    }

    // ===== fixed-point iteration y <- x - S y ; out = x - 2 S y =====
    {
        h16* ycur = sy0;
        h16* ynxt = sy1;
        const int wr = yaddr(r);
        #pragma unroll
        for (int it = 0; it < NITER; ++it) {
            const uint4* yp = (const uint4*)(ycur + p * PSH);
            float a0 = 0.f, a1 = 0.f, a2 = 0.f, a3 = 0.f;
            #pragma unroll
            for (int k = 0; k < 8; ++k) {
                uint4 yv = yp[k];
                a0 = dot2f(sreg[4 * k + 0], yv.x, a0);
                a1 = dot2f(sreg[4 * k + 1], yv.y, a1);
                a2 = dot2f(sreg[4 * k + 2], yv.z, a2);
                a3 = dot2f(sreg[4 * k + 3], yv.w, a3);
            }
            float v = (a0 + a1) + (a2 + a3);           // partial (S y)_r
            v += __shfl_xor(v, 1);
            v += __shfl_xor(v, 2);                     // full (S y)_r on 4 lanes
            if (it < NITER - 1) {
                if (p == 0) ynxt[wr] = (h16)(xr - v);
                h16* t = ycur; ycur = ynxt; ynxt = t;
                bar_lds();
            } else {
                if (p == 0) out[(size_t)r * CLS + c] = xr - 2.f * v;
            }
        }
    }
}

extern "C" void kernel_launch(void* const* d_in, const int* in_sizes, int n_in,
                              void* d_out, int out_size, void* d_ws, size_t ws_size,
                              hipStream_t stream) {
    const float* x = (const float*)d_in[0];
    const float* W = (const float*)d_in[1];
    float* out = (float*)d_out;

    const size_t smem = 65536 + 2 * 4 * PSH * 2;       // 66688 B -> 2 blocks/CU
    hipFuncSetAttribute((const void*)cayley_kernel,
                        hipFuncAttributeMaxDynamicSharedMemorySize, (int)smem);
    hipLaunchKernelGGL(cayley_kernel, dim3(CLS), dim3(1024), smem, stream, x, W, out);
}